// Round 9
// baseline (260.473 us; speedup 1.0000x reference)
//
#include <hip/hip_runtime.h>
#include <cstddef>

#define BB 4
#define CC 512
#define NN 4096

// ---- DIAGNOSTIC: outproj repeated idempotently (REP_OUT) so its true duration
// + counters surface above the ~42us workspace-fill wall. Revert next round. ----
#define REP_OUT 5

using half8  = __attribute__((ext_vector_type(8))) _Float16;
using fp16x2 = __attribute__((ext_vector_type(2))) __fp16;
using short8 = __attribute__((ext_vector_type(8))) short;
using us8    = __attribute__((ext_vector_type(8))) unsigned short;
using f32x4  = __attribute__((ext_vector_type(4))) float;
using f32x16 = __attribute__((ext_vector_type(16))) float;

__device__ __forceinline__ unsigned short f2bf(float x) {
    unsigned int u = __float_as_uint(x);
    u += 0x7fffu + ((u >> 16) & 1u);
    return (unsigned short)(u >> 16);
}

// ---------------- Kernel 0: weight conversion to fp16 ----------------
__global__ __launch_bounds__(256) void prep_kernel(
    const float* __restrict__ Wf, const float* __restrict__ Wg,
    const float* __restrict__ Wh, const float* __restrict__ Wv,
    _Float16* __restrict__ Wc16, _Float16* __restrict__ Wv16)
{
    int idx = blockIdx.x * 256 + threadIdx.x;
    int stride = gridDim.x * 256;
    const int N1 = 192 * 512, N2 = 512 * 64;
    for (int i = idx; i < N1 + N2; i += stride) {
        if (i < N1) {
            int row = i >> 9, c = i & 511;
            const float* src = (row < 64) ? Wf : ((row < 128) ? Wg : Wh);
            float sc = (row >= 64 && row < 128) ? 1.4426950408889634f : 1.0f;
            Wc16[i] = (_Float16)(sc * src[(row & 63) * 512 + c]);
        } else {
            int k = i - N1;
            Wv16[k] = (_Float16)Wv[k];
        }
    }
}

// ---------------- Kernel 1: projections f,g,h — LDS-staged fp16 MFMA ----------------
// [R1/R5 measured-best 32-i version; ~12-14us]
__global__ __launch_bounds__(256) void proj_kernel(
    const float* __restrict__ x, const _Float16* __restrict__ Wc16,
    _Float16* __restrict__ Kf, _Float16* __restrict__ Qf,
    unsigned short* __restrict__ Vt)
{
    __shared__ float xsT[2][32][68];   // [buf][i][c] (68: 16B-aligned rows, pad)
    const int t    = threadIdx.x;
    const int w    = t >> 6;
    const int lane = t & 63;
    const int lh   = lane & 15;
    const int qd   = lane >> 4;
    const int b    = blockIdx.x >> 7;
    const int i0   = (blockIdx.x & 127) << 5;

    f32x4 acc[3][2];
    #pragma unroll
    for (int ot = 0; ot < 3; ot++)
        #pragma unroll
        for (int it = 0; it < 2; it++) { acc[ot][it][0]=0.f; acc[ot][it][1]=0.f; acc[ot][it][2]=0.f; acc[ot][it][3]=0.f; }

    const int ti8 = t & 7;           // i-group of 4
    const int tc2 = t >> 3;          // c-row 0..31
    const float* xbase = x + (size_t)b*CC*NN + i0 + ti8*4;
    const _Float16* wbase = Wc16 + (size_t)(w*48 + lh)*512 + qd*8;

    float4 st0, st1;
    half8  wcur[2][3], wnxt[2][3];

#define LOADX(ck) do {                                                        \
    st0 = *(const float4*)(xbase + (size_t)((ck)*64 + tc2)*NN);               \
    st1 = *(const float4*)(xbase + (size_t)((ck)*64 + 32 + tc2)*NN);          \
} while (0)
#define STOREX(p_) do {                                                       \
    xsT[p_][ti8*4+0][tc2]    = st0.x; xsT[p_][ti8*4+1][tc2]    = st0.y;       \
    xsT[p_][ti8*4+2][tc2]    = st0.z; xsT[p_][ti8*4+3][tc2]    = st0.w;       \
    xsT[p_][ti8*4+0][32+tc2] = st1.x; xsT[p_][ti8*4+1][32+tc2] = st1.y;       \
    xsT[p_][ti8*4+2][32+tc2] = st1.z; xsT[p_][ti8*4+3][32+tc2] = st1.w;       \
} while (0)
#define LOADW(ck, WD) do {                                                    \
    _Pragma("unroll")                                                         \
    for (int ks_ = 0; ks_ < 2; ks_++)                                         \
        _Pragma("unroll")                                                     \
        for (int ot_ = 0; ot_ < 3; ot_++)                                     \
            WD[ks_][ot_] = *(const half8*)(wbase + (size_t)(ot_*16)*512 + (ck)*64 + ks_*32); \
} while (0)

    LOADX(0); STOREX(0);
    LOADW(0, wcur);
    __syncthreads();

    #pragma unroll
    for (int ck = 0; ck < 8; ck++) {
        const int p = ck & 1;
        if (ck < 7) { LOADX(ck + 1); LOADW(ck + 1, wnxt); }

        #pragma unroll
        for (int ks = 0; ks < 2; ks++) {
            half8 xf[2];
            #pragma unroll
            for (int it = 0; it < 2; it++) {
                const float* xr = &xsT[p][it*16 + lh][ks*32 + qd*8];
                f32x4 xa = *(const f32x4*)xr;
                f32x4 xb = *(const f32x4*)(xr + 4);
                union { fp16x2 h2[4]; half8 h8; } u;
                u.h2[0] = __builtin_amdgcn_cvt_pkrtz(xa[0], xa[1]);
                u.h2[1] = __builtin_amdgcn_cvt_pkrtz(xa[2], xa[3]);
                u.h2[2] = __builtin_amdgcn_cvt_pkrtz(xb[0], xb[1]);
                u.h2[3] = __builtin_amdgcn_cvt_pkrtz(xb[2], xb[3]);
                xf[it] = u.h8;
            }
            #pragma unroll
            for (int ot = 0; ot < 3; ot++)
                #pragma unroll
                for (int it = 0; it < 2; it++)
                    acc[ot][it] = __builtin_amdgcn_mfma_f32_16x16x32_f16(wcur[ks][ot], xf[it], acc[ot][it], 0, 0, 0);
        }

        if (ck < 7) {
            STOREX(p ^ 1);
            #pragma unroll
            for (int ks_ = 0; ks_ < 2; ks_++)
                #pragma unroll
                for (int ot_ = 0; ot_ < 3; ot_++)
                    wcur[ks_][ot_] = wnxt[ks_][ot_];
        }
        __syncthreads();
    }
#undef LOADX
#undef STOREX
#undef LOADW

    #pragma unroll
    for (int ot = 0; ot < 3; ot++) {
        int g16 = w*3 + ot;          // 0..11
        int m   = g16 >> 2;
        int obase = (g16 & 3)*16 + qd*4;
        #pragma unroll
        for (int it = 0; it < 2; it++) {
            int ig = i0 + it*16 + lh;
            #pragma unroll
            for (int r = 0; r < 4; r++) {
                float v = acc[ot][it][r];
                int ol = obase + r;
                if (m == 0)       Kf[((size_t)b*NN + ig)*64 + ol] = (_Float16)v;
                else if (m == 1)  Qf[((size_t)b*NN + ig)*64 + ol] = (_Float16)v;
                else              Vt[((size_t)b*64 + ol)*NN + ig] = f2bf(v);
            }
        }
    }
}

// ---------------- Kernel 2: split-K flash attention, 32x32 swapped-QK^T ----------------
// [R1 measured-best version (original swizzle) — part of the 162.7us base config]
template<int SPLITS>
__global__ __launch_bounds__(256, 3) void attn_kernel(
    const _Float16* __restrict__ Kf, const _Float16* __restrict__ Qf,
    const unsigned short* __restrict__ Vt,
    _Float16* __restrict__ Po16, float* __restrict__ Pl)
{
    static_assert(NN % SPLITS == 0, "split");
    constexpr int KS  = NN / SPLITS;   // keys per split
    constexpr int NCH = KS / 64;       // 64-key chunks

    __shared__ __align__(16) unsigned short Kb2[2][64*64];  // [i][c] swizzled 16B blocks
    __shared__ __align__(16) unsigned short Vb2[2][64*64];  // [d][i] swizzled 16B blocks

    const int t    = threadIdx.x;
    const int wv   = t >> 6;
    const int lane = t & 63;
    const int il   = lane & 31;
    const int h    = lane >> 5;

    const int p  = blockIdx.x;
    const int v  = (p & 7) * (SPLITS * 16) + (p >> 3);
    const int jt = v & 31;
    const int bs = v >> 5;
    const int b  = bs / SPLITS;
    const int s  = bs % SPLITS;
    const int j0w  = jt*128 + wv*32;
    const int koff = s * KS;

    half8 qfr[4];
    {
        const _Float16* qp = Qf + ((size_t)b*NN + j0w + il)*64 + h*8;
        #pragma unroll
        for (int sl = 0; sl < 4; sl++) qfr[sl] = *(const half8*)(qp + sl*16);
    }

    f32x16 o_acc[2];
    #pragma unroll
    for (int dt = 0; dt < 2; dt++)
        #pragma unroll
        for (int r = 0; r < 16; r++) o_acc[dt][r] = 0.f;
    float l4[4] = {0.f, 0.f, 0.f, 0.f};

    const int slot0 = t, slot1 = 256 + t;
    const int ik0 = slot0 >> 3, sw0 = ((slot0 & 7) ^ (ik0 & 7)) << 3;
    const int ik1 = slot1 >> 3, sw1 = ((slot1 & 7) ^ (ik1 & 7)) << 3;
    const _Float16*       gk0 = Kf + ((size_t)b*NN + koff + ik0)*64 + sw0;
    const _Float16*       gk1 = Kf + ((size_t)b*NN + koff + ik1)*64 + sw1;
    const unsigned short* gv0 = Vt + ((size_t)b*64 + ik0)*NN + koff + sw0;
    const unsigned short* gv1 = Vt + ((size_t)b*64 + ik1)*NN + koff + sw1;

#define STAGE(ck, pb) do {                                                          \
    const size_t o64_ = (size_t)(ck)*64;                                            \
    __builtin_amdgcn_global_load_lds(                                               \
        (const __attribute__((address_space(1))) void*)(gk0 + o64_*64),             \
        (__attribute__((address_space(3))) void*)&Kb2[pb][(wv*64)*8], 16, 0, 0);    \
    __builtin_amdgcn_global_load_lds(                                               \
        (const __attribute__((address_space(1))) void*)(gk1 + o64_*64),             \
        (__attribute__((address_space(3))) void*)&Kb2[pb][(256 + wv*64)*8], 16, 0, 0); \
    __builtin_amdgcn_global_load_lds(                                               \
        (const __attribute__((address_space(1))) void*)(gv0 + o64_),                \
        (__attribute__((address_space(3))) void*)&Vb2[pb][(wv*64)*8], 16, 0, 0);    \
    __builtin_amdgcn_global_load_lds(                                               \
        (const __attribute__((address_space(1))) void*)(gv1 + o64_),                \
        (__attribute__((address_space(3))) void*)&Vb2[pb][(256 + wv*64)*8], 16, 0, 0); \
    } while (0)

    STAGE(0, 0);
    __syncthreads();

    for (int ck = 0; ck < NCH; ck++) {
        const int cb = ck & 1;
        if (ck + 1 < NCH) STAGE(ck + 1, cb ^ 1);

        const unsigned short* Kb = Kb2[cb];
        const unsigned short* Vb = Vb2[cb];

        #pragma unroll
        for (int isub = 0; isub < 2; isub++) {
            const int irow = isub*32 + il;
            const unsigned short* kr = Kb + irow*64;
            f32x16 sc;
            #pragma unroll
            for (int r = 0; r < 16; r++) sc[r] = 0.f;
            #pragma unroll
            for (int sl = 0; sl < 4; sl++) {
                half8 kf = *(const half8*)(kr + (((sl*2 + h) ^ (irow & 7)) << 3));
                sc = __builtin_amdgcn_mfma_f32_32x32x16_f16(kf, qfr[sl], sc, 0, 0, 0);
            }

            float pq[16];
            #pragma unroll
            for (int r = 0; r < 16; r++) pq[r] = exp2f(sc[r]);
            #pragma unroll
            for (int r = 0; r < 16; r++) l4[r & 3] += pq[r];

            unsigned wA[8];
            #pragma unroll
            for (int k = 0; k < 8; k++)
                asm("v_cvt_pk_bf16_f32 %0, %1, %2" : "=v"(wA[k]) : "v"(pq[2*k]), "v"(pq[2*k+1]));
            asm("v_permlane32_swap_b32 %0, %1" : "+v"(wA[0]), "+v"(wA[2]));
            asm("v_permlane32_swap_b32 %0, %1" : "+v"(wA[1]), "+v"(wA[3]));
            asm("v_permlane32_swap_b32 %0, %1" : "+v"(wA[4]), "+v"(wA[6]));
            asm("v_permlane32_swap_b32 %0, %1" : "+v"(wA[5]), "+v"(wA[7]));

            union { unsigned u[4]; short8 s8; } pa0, pa1;
            pa0.u[0]=wA[0]; pa0.u[1]=wA[1]; pa0.u[2]=wA[2]; pa0.u[3]=wA[3];
            pa1.u[0]=wA[4]; pa1.u[1]=wA[5]; pa1.u[2]=wA[6]; pa1.u[3]=wA[7];

            #pragma unroll
            for (int isl = 0; isl < 2; isl++) {
                const short8 paf = isl ? pa1.s8 : pa0.s8;
                const int vc = isub*4 + isl*2 + h;
                #pragma unroll
                for (int dt = 0; dt < 2; dt++) {
                    const int drow = dt*32 + il;
                    short8 vf = *(const short8*)(Vb + drow*64 + ((vc ^ (drow & 7)) << 3));
                    o_acc[dt] = __builtin_amdgcn_mfma_f32_32x32x16_bf16(paf, vf, o_acc[dt], 0, 0, 0);
                }
            }
        }
        __syncthreads();   // drains staged loads (vmcnt) + orders buffer reuse
    }
#undef STAGE

    float l_acc  = (l4[0] + l4[1]) + (l4[2] + l4[3]);
    float l_full = l_acc + __shfl_xor(l_acc, 32);
    float inv = 1.0f / l_full;

    const size_t pbase = (size_t)(s*4 + b)*NN + j0w;
    #pragma unroll
    for (int r = 0; r < 16; r++) {
        const int jr = (r & 3) + 8*(r >> 2) + 4*h;
        const float invr = __shfl(inv, jr);
        #pragma unroll
        for (int dt = 0; dt < 2; dt++)
            Po16[(pbase + jr)*64 + dt*32 + il] = (_Float16)(o_acc[dt][r] * invr);
    }
    if (h == 0) Pl[pbase + il] = l_full;
}

// ---------------- Kernel 3: fused combine + output projection + residual ----------------
// [R7 deduped/grid-1024 version, wrapped in REP_OUT idempotent reps for measurement]
template<int SPLITS>
__global__ __launch_bounds__(256) void outproj_kernel(
    const _Float16* __restrict__ Po16, const float* __restrict__ Pl,
    const _Float16* __restrict__ Wv16,
    const float* __restrict__ x, const float* __restrict__ gamma,
    float* __restrict__ out1, float* __restrict__ out2)
{
    __shared__ __align__(16) _Float16 sbM[16][72];  // merged sa^T [j][d], pad 72
    __shared__ float Osh[4][16][20];                // per-wave C-tile transpose
    const int t    = threadIdx.x;
    const int w    = t >> 6;
    const int lane = t & 63;
    const int lh   = lane & 15;
    const int qd   = lane >> 4;
    const int b    = blockIdx.x >> 8;
    const int j0   = (blockIdx.x & 255) << 4;
    const float g  = gamma[0];

    #pragma unroll 1
    for (int rep = 0; rep < REP_OUT; ++rep) {
        asm volatile("" ::: "memory");   // block cross-rep CSE/hoisting

        // ---- Phase 1: deduped split-K merge (threads 0..127; j = t&15, d8 = t>>4) ----
        if (t < 128) {
            const int jj = t & 15, d8 = t >> 4;
            float os[8];
            #pragma unroll
            for (int k = 0; k < 8; k++) os[k] = 0.f;
            float lsum = 0.f;
            #pragma unroll
            for (int s = 0; s < SPLITS; s++) {
                const size_t base = (size_t)(s*4 + b)*NN + j0 + jj;
                half8 vv = *(const half8*)(Po16 + base*64 + d8*8);
                float l  = Pl[base];
                #pragma unroll
                for (int k = 0; k < 8; k++) os[k] = fmaf(l, (float)vv[k], os[k]);
                lsum += l;
            }
            const float inv = 1.0f / lsum;
            union { fp16x2 h2[4]; half8 h8; } u;
            #pragma unroll
            for (int k = 0; k < 4; k++)
                u.h2[k] = __builtin_amdgcn_cvt_pkrtz(os[2*k]*inv, os[2*k+1]*inv);
            *(half8*)&sbM[jj][d8*8] = u.h8;
        }
        __syncthreads();

        const half8 sb0 = *(const half8*)&sbM[lh][qd*8];
        const half8 sb1 = *(const half8*)&sbM[lh][32 + qd*8];

        const int o_loc = lane >> 2;           // 0..15
        const int j4    = (lane & 3) * 4;      // 0,4,8,12

        #pragma unroll 2
        for (int ot8 = 0; ot8 < 8; ot8++) {
            const int ot = w*8 + ot8;

            // x residual load first: HBM latency hides under MFMA + transpose
            const size_t idx = ((size_t)b*CC + ot*16 + o_loc)*NN + j0 + j4;
            const f32x4 xv = *(const f32x4*)(x + idx);

            const size_t wbase = (size_t)(ot*16 + lh)*64 + qd*8;
            half8 a0 = *(const half8*)(Wv16 + wbase);
            half8 a1 = *(const half8*)(Wv16 + wbase + 32);

            f32x4 acc;
            acc[0]=0.f; acc[1]=0.f; acc[2]=0.f; acc[3]=0.f;
            acc = __builtin_amdgcn_mfma_f32_16x16x32_f16(a0, sb0, acc, 0, 0, 0);
            acc = __builtin_amdgcn_mfma_f32_16x16x32_f16(a1, sb1, acc, 0, 0, 0);

            #pragma unroll
            for (int r = 0; r < 4; r++)
                Osh[w][qd*4 + r][lh] = acc[r];
            asm volatile("s_waitcnt lgkmcnt(0)" ::: "memory");

            f32x4 vv = *(const f32x4*)&Osh[w][o_loc][j4];
            *(f32x4*)(out2 + idx) = vv;
            f32x4 r1;
            r1[0] = fmaf(g, vv[0], xv[0]); r1[1] = fmaf(g, vv[1], xv[1]);
            r1[2] = fmaf(g, vv[2], xv[2]); r1[3] = fmaf(g, vv[3], xv[3]);
            *(f32x4*)(out1 + idx) = r1;
            asm volatile("s_waitcnt lgkmcnt(0)" ::: "memory");  // WAR guard before next Osh write
        }

        __syncthreads();   // order sbM reuse across reps (cross-wave)
    }
}

extern "C" void kernel_launch(void* const* d_in, const int* in_sizes, int n_in,
                              void* d_out, int out_size, void* d_ws, size_t ws_size,
                              hipStream_t stream) {
    const float* x     = (const float*)d_in[0];
    const float* Wf    = (const float*)d_in[1];
    const float* Wg    = (const float*)d_in[2];
    const float* Wh    = (const float*)d_in[3];
    const float* Wv    = (const float*)d_in[4];
    const float* gamma = (const float*)d_in[5];

    float* out1 = (float*)d_out;
    float* out2 = out1 + (size_t)BB*CC*NN;

    const size_t BND = (size_t)BB*NN*64;   // 1M elements
    const size_t need8 = BND*2*3 + BND*2*8 + (size_t)8*BB*NN*4
                       + (size_t)192*512*2 + (size_t)512*64*2;
    const int SPL = (ws_size >= need8) ? 8 : 4;

    char* wp = (char*)d_ws;
    _Float16*       Kf   = (_Float16*)wp;        wp += BND*2;            // 2 MB
    _Float16*       Qf   = (_Float16*)wp;        wp += BND*2;            // 2 MB
    unsigned short* Vt   = (unsigned short*)wp;  wp += BND*2;            // 2 MB
    _Float16*       Po16 = (_Float16*)wp;        wp += BND*2*SPL;        // 8/16 MB
    float*          Pl   = (float*)wp;           wp += (size_t)SPL*BB*NN*4;
    _Float16*       Wc16 = (_Float16*)wp;        wp += (size_t)192*512*2;
    _Float16*       Wv16 = (_Float16*)wp;

    prep_kernel<<<dim3(64), dim3(256), 0, stream>>>(Wf, Wg, Wh, Wv, Wc16, Wv16);
    proj_kernel<<<dim3(BB*128), dim3(256), 0, stream>>>(x, Wc16, Kf, Qf, Vt);
    if (SPL == 8) {
        attn_kernel<8><<<dim3(128*8), dim3(256), 0, stream>>>(Kf, Qf, Vt, Po16, Pl);
        outproj_kernel<8><<<dim3(BB*256), dim3(256), 0, stream>>>(Po16, Pl, Wv16, x, gamma, out1, out2);
    } else {
        attn_kernel<4><<<dim3(128*4), dim3(256), 0, stream>>>(Kf, Qf, Vt, Po16, Pl);
        outproj_kernel<4><<<dim3(BB*256), dim3(256), 0, stream>>>(Po16, Pl, Wv16, x, gamma, out1, out2);
    }
}

// Round 10
// 203.741 us; speedup vs baseline: 1.2784x; 1.2784x over previous
//
#include <hip/hip_runtime.h>
#include <cstddef>

#define BB 4
#define CC 512
#define NN 4096

using half8  = __attribute__((ext_vector_type(8))) _Float16;
using fp16x2 = __attribute__((ext_vector_type(2))) __fp16;
using short8 = __attribute__((ext_vector_type(8))) short;
using us8    = __attribute__((ext_vector_type(8))) unsigned short;
using f32x4  = __attribute__((ext_vector_type(4))) float;
using f32x16 = __attribute__((ext_vector_type(16))) float;

__device__ __forceinline__ unsigned short f2bf(float x) {
    unsigned int u = __float_as_uint(x);
    u += 0x7fffu + ((u >> 16) & 1u);
    return (unsigned short)(u >> 16);
}

// ---------------- Kernel 0: weight conversion to fp16 ----------------
__global__ __launch_bounds__(256) void prep_kernel(
    const float* __restrict__ Wf, const float* __restrict__ Wg,
    const float* __restrict__ Wh, const float* __restrict__ Wv,
    _Float16* __restrict__ Wc16, _Float16* __restrict__ Wv16)
{
    int idx = blockIdx.x * 256 + threadIdx.x;
    int stride = gridDim.x * 256;
    const int N1 = 192 * 512, N2 = 512 * 64;
    for (int i = idx; i < N1 + N2; i += stride) {
        if (i < N1) {
            int row = i >> 9, c = i & 511;
            const float* src = (row < 64) ? Wf : ((row < 128) ? Wg : Wh);
            float sc = (row >= 64 && row < 128) ? 1.4426950408889634f : 1.0f;
            Wc16[i] = (_Float16)(sc * src[(row & 63) * 512 + c]);
        } else {
            int k = i - N1;
            Wv16[k] = (_Float16)Wv[k];
        }
    }
}

// ---------------- Kernel 1: projections f,g,h — LDS-staged fp16 MFMA ----------------
// [R1/R5 measured-best 32-i version; ~12us, floor ~7 — not the bottleneck]
__global__ __launch_bounds__(256) void proj_kernel(
    const float* __restrict__ x, const _Float16* __restrict__ Wc16,
    _Float16* __restrict__ Kf, _Float16* __restrict__ Qf,
    unsigned short* __restrict__ Vt)
{
    __shared__ float xsT[2][32][68];   // [buf][i][c] (68: 16B-aligned rows, pad)
    const int t    = threadIdx.x;
    const int w    = t >> 6;
    const int lane = t & 63;
    const int lh   = lane & 15;
    const int qd   = lane >> 4;
    const int b    = blockIdx.x >> 7;
    const int i0   = (blockIdx.x & 127) << 5;

    f32x4 acc[3][2];
    #pragma unroll
    for (int ot = 0; ot < 3; ot++)
        #pragma unroll
        for (int it = 0; it < 2; it++) { acc[ot][it][0]=0.f; acc[ot][it][1]=0.f; acc[ot][it][2]=0.f; acc[ot][it][3]=0.f; }

    const int ti8 = t & 7;           // i-group of 4
    const int tc2 = t >> 3;          // c-row 0..31
    const float* xbase = x + (size_t)b*CC*NN + i0 + ti8*4;
    const _Float16* wbase = Wc16 + (size_t)(w*48 + lh)*512 + qd*8;

    float4 st0, st1;
    half8  wcur[2][3], wnxt[2][3];

#define LOADX(ck) do {                                                        \
    st0 = *(const float4*)(xbase + (size_t)((ck)*64 + tc2)*NN);               \
    st1 = *(const float4*)(xbase + (size_t)((ck)*64 + 32 + tc2)*NN);          \
} while (0)
#define STOREX(p_) do {                                                       \
    xsT[p_][ti8*4+0][tc2]    = st0.x; xsT[p_][ti8*4+1][tc2]    = st0.y;       \
    xsT[p_][ti8*4+2][tc2]    = st0.z; xsT[p_][ti8*4+3][tc2]    = st0.w;       \
    xsT[p_][ti8*4+0][32+tc2] = st1.x; xsT[p_][ti8*4+1][32+tc2] = st1.y;       \
    xsT[p_][ti8*4+2][32+tc2] = st1.z; xsT[p_][ti8*4+3][32+tc2] = st1.w;       \
} while (0)
#define LOADW(ck, WD) do {                                                    \
    _Pragma("unroll")                                                         \
    for (int ks_ = 0; ks_ < 2; ks_++)                                         \
        _Pragma("unroll")                                                     \
        for (int ot_ = 0; ot_ < 3; ot_++)                                     \
            WD[ks_][ot_] = *(const half8*)(wbase + (size_t)(ot_*16)*512 + (ck)*64 + ks_*32); \
} while (0)

    LOADX(0); STOREX(0);
    LOADW(0, wcur);
    __syncthreads();

    #pragma unroll
    for (int ck = 0; ck < 8; ck++) {
        const int p = ck & 1;
        if (ck < 7) { LOADX(ck + 1); LOADW(ck + 1, wnxt); }

        #pragma unroll
        for (int ks = 0; ks < 2; ks++) {
            half8 xf[2];
            #pragma unroll
            for (int it = 0; it < 2; it++) {
                const float* xr = &xsT[p][it*16 + lh][ks*32 + qd*8];
                f32x4 xa = *(const f32x4*)xr;
                f32x4 xb = *(const f32x4*)(xr + 4);
                union { fp16x2 h2[4]; half8 h8; } u;
                u.h2[0] = __builtin_amdgcn_cvt_pkrtz(xa[0], xa[1]);
                u.h2[1] = __builtin_amdgcn_cvt_pkrtz(xa[2], xa[3]);
                u.h2[2] = __builtin_amdgcn_cvt_pkrtz(xb[0], xb[1]);
                u.h2[3] = __builtin_amdgcn_cvt_pkrtz(xb[2], xb[3]);
                xf[it] = u.h8;
            }
            #pragma unroll
            for (int ot = 0; ot < 3; ot++)
                #pragma unroll
                for (int it = 0; it < 2; it++)
                    acc[ot][it] = __builtin_amdgcn_mfma_f32_16x16x32_f16(wcur[ks][ot], xf[it], acc[ot][it], 0, 0, 0);
        }

        if (ck < 7) {
            STOREX(p ^ 1);
            #pragma unroll
            for (int ks_ = 0; ks_ < 2; ks_++)
                #pragma unroll
                for (int ot_ = 0; ot_ < 3; ot_++)
                    wcur[ks_][ot_] = wnxt[ks_][ot_];
        }
        __syncthreads();
    }
#undef LOADX
#undef STOREX
#undef LOADW

    #pragma unroll
    for (int ot = 0; ot < 3; ot++) {
        int g16 = w*3 + ot;          // 0..11
        int m   = g16 >> 2;
        int obase = (g16 & 3)*16 + qd*4;
        #pragma unroll
        for (int it = 0; it < 2; it++) {
            int ig = i0 + it*16 + lh;
            #pragma unroll
            for (int r = 0; r < 4; r++) {
                float v = acc[ot][it][r];
                int ol = obase + r;
                if (m == 0)       Kf[((size_t)b*NN + ig)*64 + ol] = (_Float16)v;
                else if (m == 1)  Qf[((size_t)b*NN + ig)*64 + ol] = (_Float16)v;
                else              Vt[((size_t)b*64 + ol)*NN + ig] = f2bf(v);
            }
        }
    }
}

// ---------------- Kernel 2: split-K flash attention — DIRECT-FROM-L2, no LDS ----------------
// THIS ROUND: K/V per (b,s) is only 128 KB and L2-resident (shared by the 32
// co-XCD j-blocks), so the LDS staging + per-chunk vmcnt(0)+barrier lockstep was
// pure overhead (measured: chunk period 1450cy predicted vs ~4x observed; R1-R6
// scheduling tweaks all neutral because the barrier cadence set the period).
// Now each lane loads its MFMA fragments directly from global (16B contiguous,
// identical bytes the LDS held). No LDS, no barriers, independent waves,
// 16 waves/CU. FP op order unchanged -> bit-identical output.
template<int SPLITS>
__global__ __launch_bounds__(256, 4) void attn_kernel(
    const _Float16* __restrict__ Kf, const _Float16* __restrict__ Qf,
    const unsigned short* __restrict__ Vt,
    _Float16* __restrict__ Po16, float* __restrict__ Pl)
{
    static_assert(NN % SPLITS == 0, "split");
    constexpr int KS = NN / SPLITS;   // keys per split
    constexpr int NT = KS / 32;       // 32-key MFMA tiles

    const int t    = threadIdx.x;
    const int wv   = t >> 6;
    const int lane = t & 63;
    const int il   = lane & 31;
    const int h    = lane >> 5;

    // bijective XCD swizzle: blocks sharing (b,s) (same K/V) land on one XCD
    const int p  = blockIdx.x;
    const int v  = (p & 7) * (SPLITS * 16) + (p >> 3);
    const int jt = v & 31;
    const int bs = v >> 5;
    const int b  = bs / SPLITS;
    const int s  = bs % SPLITS;
    const int j0w  = jt*128 + wv*32;
    const int koff = s * KS;

    // Q fragments (B-operand), hoisted: lane supplies Q[c = sl*16 + h*8 + e][j = j0w + il]
    half8 qfr[4];
    {
        const _Float16* qp = Qf + ((size_t)b*NN + j0w + il)*64 + h*8;
        #pragma unroll
        for (int sl = 0; sl < 4; sl++) qfr[sl] = *(const half8*)(qp + sl*16);
    }

    f32x16 o_acc[2];
    #pragma unroll
    for (int dt = 0; dt < 2; dt++)
        #pragma unroll
        for (int r = 0; r < 16; r++) o_acc[dt][r] = 0.f;
    float l4[4] = {0.f, 0.f, 0.f, 0.f};

    // Direct-load bases.
    // K A-frag: lane (il,h) reads K[koff + nt*32 + il][sl*16 + h*8 .. +7]  (16B)
    // V B-frag: lane (il,h) reads Vt[d = dt*32 + il][koff + nt*32 + isl*16 + h*8 .. +7]
    const _Float16*       Kb  = Kf + ((size_t)b*NN + koff + il)*64 + h*8;
    const unsigned short* Vb0 = Vt + ((size_t)(b*64      + il))*NN + koff + h*8;
    const unsigned short* Vb1 = Vt + ((size_t)(b*64 + 32 + il))*NN + koff + h*8;

    #pragma unroll 2
    for (int nt = 0; nt < NT; ++nt) {
        const _Float16* kp = Kb + (size_t)(nt*32)*64;
        const int ib = nt*32;

        // issue all 8 fragment loads up front; QK waits only on the K four,
        // softmax VALU (~300cy) covers the V four.
        half8  kf0 = *(const half8*)(kp);
        half8  kf1 = *(const half8*)(kp + 16);
        half8  kf2 = *(const half8*)(kp + 32);
        half8  kf3 = *(const half8*)(kp + 48);
        short8 v00 = *(const short8*)(Vb0 + ib);        // isl=0, dt=0
        short8 v01 = *(const short8*)(Vb1 + ib);        // isl=0, dt=1
        short8 v10 = *(const short8*)(Vb0 + ib + 16);   // isl=1, dt=0
        short8 v11 = *(const short8*)(Vb1 + ib + 16);   // isl=1, dt=1

        // ---- S^T tile: A = K[i][c] (i = nt*32 + il), B = Q[c][j] ----
        f32x16 sc;
        #pragma unroll
        for (int r = 0; r < 16; r++) sc[r] = 0.f;
        sc = __builtin_amdgcn_mfma_f32_32x32x16_f16(kf0, qfr[0], sc, 0, 0, 0);
        sc = __builtin_amdgcn_mfma_f32_32x32x16_f16(kf1, qfr[1], sc, 0, 0, 0);
        sc = __builtin_amdgcn_mfma_f32_32x32x16_f16(kf2, qfr[2], sc, 0, 0, 0);
        sc = __builtin_amdgcn_mfma_f32_32x32x16_f16(kf3, qfr[3], sc, 0, 0, 0);

        // ---- softmax numerator, lane-local (j = il); rows i = (r&3)+8*(r>>2)+4h ----
        float pq[16];
        #pragma unroll
        for (int r = 0; r < 16; r++) pq[r] = exp2f(sc[r]);
        #pragma unroll
        for (int r = 0; r < 16; r++) l4[r & 3] += pq[r];

        // ---- P -> bf16 A-fragments in-register (cvt_pk + permlane32_swap) ----
        unsigned wA[8];
        #pragma unroll
        for (int k = 0; k < 8; k++)
            asm("v_cvt_pk_bf16_f32 %0, %1, %2" : "=v"(wA[k]) : "v"(pq[2*k]), "v"(pq[2*k+1]));
        asm("v_permlane32_swap_b32 %0, %1" : "+v"(wA[0]), "+v"(wA[2]));
        asm("v_permlane32_swap_b32 %0, %1" : "+v"(wA[1]), "+v"(wA[3]));
        asm("v_permlane32_swap_b32 %0, %1" : "+v"(wA[4]), "+v"(wA[6]));
        asm("v_permlane32_swap_b32 %0, %1" : "+v"(wA[5]), "+v"(wA[7]));

        union { unsigned u[4]; short8 s8; } pa0, pa1;
        pa0.u[0]=wA[0]; pa0.u[1]=wA[1]; pa0.u[2]=wA[2]; pa0.u[3]=wA[3];
        pa1.u[0]=wA[4]; pa1.u[1]=wA[5]; pa1.u[2]=wA[6]; pa1.u[3]=wA[7];

        // ---- PV: A = P^T[j][i], B = V[i][d] ----
        o_acc[0] = __builtin_amdgcn_mfma_f32_32x32x16_bf16(pa0.s8, v00, o_acc[0], 0, 0, 0);
        o_acc[1] = __builtin_amdgcn_mfma_f32_32x32x16_bf16(pa0.s8, v01, o_acc[1], 0, 0, 0);
        o_acc[0] = __builtin_amdgcn_mfma_f32_32x32x16_bf16(pa1.s8, v10, o_acc[0], 0, 0, 0);
        o_acc[1] = __builtin_amdgcn_mfma_f32_32x32x16_bf16(pa1.s8, v11, o_acc[1], 0, 0, 0);
    }

    // ---- epilogue: combine halves, normalize per-split, store ----
    float l_acc  = (l4[0] + l4[1]) + (l4[2] + l4[3]);
    float l_full = l_acc + __shfl_xor(l_acc, 32);
    float inv = 1.0f / l_full;

    const size_t pbase = (size_t)(s*4 + b)*NN + j0w;
    #pragma unroll
    for (int r = 0; r < 16; r++) {
        const int jr = (r & 3) + 8*(r >> 2) + 4*h;
        const float invr = __shfl(inv, jr);
        #pragma unroll
        for (int dt = 0; dt < 2; dt++)
            Po16[(pbase + jr)*64 + dt*32 + il] = (_Float16)(o_acc[dt][r] * invr);
    }
    if (h == 0) Pl[pbase + il] = l_full;
}

// ---------------- Kernel 3: fused combine + output projection + residual ----------------
// [R7 deduped/grid-1024 version: split-K merge computed once per block into LDS,
//  x-loads hoisted. Measured R9: ~25us warm, 56% BW, ~70% of traffic floor.]
template<int SPLITS>
__global__ __launch_bounds__(256) void outproj_kernel(
    const _Float16* __restrict__ Po16, const float* __restrict__ Pl,
    const _Float16* __restrict__ Wv16,
    const float* __restrict__ x, const float* __restrict__ gamma,
    float* __restrict__ out1, float* __restrict__ out2)
{
    __shared__ __align__(16) _Float16 sbM[16][72];  // merged sa^T [j][d], pad 72
    __shared__ float Osh[4][16][20];                // per-wave C-tile transpose
    const int t    = threadIdx.x;
    const int w    = t >> 6;
    const int lane = t & 63;
    const int lh   = lane & 15;
    const int qd   = lane >> 4;
    const int b    = blockIdx.x >> 8;
    const int j0   = (blockIdx.x & 255) << 4;
    const float g  = gamma[0];

    // ---- Phase 1: deduped split-K merge (threads 0..127; j = t&15, d8 = t>>4) ----
    if (t < 128) {
        const int jj = t & 15, d8 = t >> 4;
        float os[8];
        #pragma unroll
        for (int k = 0; k < 8; k++) os[k] = 0.f;
        float lsum = 0.f;
        #pragma unroll
        for (int s = 0; s < SPLITS; s++) {
            const size_t base = (size_t)(s*4 + b)*NN + j0 + jj;
            half8 vv = *(const half8*)(Po16 + base*64 + d8*8);
            float l  = Pl[base];
            #pragma unroll
            for (int k = 0; k < 8; k++) os[k] = fmaf(l, (float)vv[k], os[k]);
            lsum += l;
        }
        const float inv = 1.0f / lsum;
        union { fp16x2 h2[4]; half8 h8; } u;
        #pragma unroll
        for (int k = 0; k < 4; k++)
            u.h2[k] = __builtin_amdgcn_cvt_pkrtz(os[2*k]*inv, os[2*k+1]*inv);
        *(half8*)&sbM[jj][d8*8] = u.h8;
    }
    __syncthreads();

    const half8 sb0 = *(const half8*)&sbM[lh][qd*8];
    const half8 sb1 = *(const half8*)&sbM[lh][32 + qd*8];

    const int o_loc = lane >> 2;           // 0..15
    const int j4    = (lane & 3) * 4;      // 0,4,8,12

    #pragma unroll 2
    for (int ot8 = 0; ot8 < 8; ot8++) {
        const int ot = w*8 + ot8;

        // x residual load first: HBM latency hides under MFMA + transpose
        const size_t idx = ((size_t)b*CC + ot*16 + o_loc)*NN + j0 + j4;
        const f32x4 xv = *(const f32x4*)(x + idx);

        const size_t wbase = (size_t)(ot*16 + lh)*64 + qd*8;
        half8 a0 = *(const half8*)(Wv16 + wbase);
        half8 a1 = *(const half8*)(Wv16 + wbase + 32);

        f32x4 acc;
        acc[0]=0.f; acc[1]=0.f; acc[2]=0.f; acc[3]=0.f;
        acc = __builtin_amdgcn_mfma_f32_16x16x32_f16(a0, sb0, acc, 0, 0, 0);
        acc = __builtin_amdgcn_mfma_f32_16x16x32_f16(a1, sb1, acc, 0, 0, 0);

        #pragma unroll
        for (int r = 0; r < 4; r++)
            Osh[w][qd*4 + r][lh] = acc[r];
        asm volatile("s_waitcnt lgkmcnt(0)" ::: "memory");

        f32x4 vv = *(const f32x4*)&Osh[w][o_loc][j4];
        *(f32x4*)(out2 + idx) = vv;
        f32x4 r1;
        r1[0] = fmaf(g, vv[0], xv[0]); r1[1] = fmaf(g, vv[1], xv[1]);
        r1[2] = fmaf(g, vv[2], xv[2]); r1[3] = fmaf(g, vv[3], xv[3]);
        *(f32x4*)(out1 + idx) = r1;
        asm volatile("s_waitcnt lgkmcnt(0)" ::: "memory");  // WAR guard before next Osh write
    }
}

extern "C" void kernel_launch(void* const* d_in, const int* in_sizes, int n_in,
                              void* d_out, int out_size, void* d_ws, size_t ws_size,
                              hipStream_t stream) {
    const float* x     = (const float*)d_in[0];
    const float* Wf    = (const float*)d_in[1];
    const float* Wg    = (const float*)d_in[2];
    const float* Wh    = (const float*)d_in[3];
    const float* Wv    = (const float*)d_in[4];
    const float* gamma = (const float*)d_in[5];

    float* out1 = (float*)d_out;
    float* out2 = out1 + (size_t)BB*CC*NN;

    const size_t BND = (size_t)BB*NN*64;   // 1M elements
    const size_t need8 = BND*2*3 + BND*2*8 + (size_t)8*BB*NN*4
                       + (size_t)192*512*2 + (size_t)512*64*2;
    const int SPL = (ws_size >= need8) ? 8 : 4;

    char* wp = (char*)d_ws;
    _Float16*       Kf   = (_Float16*)wp;        wp += BND*2;            // 2 MB
    _Float16*       Qf   = (_Float16*)wp;        wp += BND*2;            // 2 MB
    unsigned short* Vt   = (unsigned short*)wp;  wp += BND*2;            // 2 MB
    _Float16*       Po16 = (_Float16*)wp;        wp += BND*2*SPL;        // 8/16 MB
    float*          Pl   = (float*)wp;           wp += (size_t)SPL*BB*NN*4;
    _Float16*       Wc16 = (_Float16*)wp;        wp += (size_t)192*512*2;
    _Float16*       Wv16 = (_Float16*)wp;

    prep_kernel<<<dim3(64), dim3(256), 0, stream>>>(Wf, Wg, Wh, Wv, Wc16, Wv16);
    proj_kernel<<<dim3(BB*128), dim3(256), 0, stream>>>(x, Wc16, Kf, Qf, Vt);
    if (SPL == 8) {
        attn_kernel<8><<<dim3(128*8), dim3(256), 0, stream>>>(Kf, Qf, Vt, Po16, Pl);
        outproj_kernel<8><<<dim3(BB*256), dim3(256), 0, stream>>>(Po16, Pl, Wv16, x, gamma, out1, out2);
    } else {
        attn_kernel<4><<<dim3(128*4), dim3(256), 0, stream>>>(Kf, Qf, Vt, Po16, Pl);
        outproj_kernel<4><<<dim3(BB*256), dim3(256), 0, stream>>>(Po16, Pl, Wv16, x, gamma, out1, out2);
    }
}

// Round 11
// 198.489 us; speedup vs baseline: 1.3123x; 1.0265x over previous
//
#include <hip/hip_runtime.h>
#include <cstddef>

#define BB 4
#define CC 512
#define NN 4096

using half8  = __attribute__((ext_vector_type(8))) _Float16;
using fp16x2 = __attribute__((ext_vector_type(2))) __fp16;
using short8 = __attribute__((ext_vector_type(8))) short;
using us8    = __attribute__((ext_vector_type(8))) unsigned short;
using f32x4  = __attribute__((ext_vector_type(4))) float;
using f32x16 = __attribute__((ext_vector_type(16))) float;

__device__ __forceinline__ unsigned short f2bf(float x) {
    unsigned int u = __float_as_uint(x);
    u += 0x7fffu + ((u >> 16) & 1u);
    return (unsigned short)(u >> 16);
}

// ---------------- Kernel 0: weight conversion to fp16 ----------------
__global__ __launch_bounds__(256) void prep_kernel(
    const float* __restrict__ Wf, const float* __restrict__ Wg,
    const float* __restrict__ Wh, const float* __restrict__ Wv,
    _Float16* __restrict__ Wc16, _Float16* __restrict__ Wv16)
{
    int idx = blockIdx.x * 256 + threadIdx.x;
    int stride = gridDim.x * 256;
    const int N1 = 192 * 512, N2 = 512 * 64;
    for (int i = idx; i < N1 + N2; i += stride) {
        if (i < N1) {
            int row = i >> 9, c = i & 511;
            const float* src = (row < 64) ? Wf : ((row < 128) ? Wg : Wh);
            float sc = (row >= 64 && row < 128) ? 1.4426950408889634f : 1.0f;
            Wc16[i] = (_Float16)(sc * src[(row & 63) * 512 + c]);
        } else {
            int k = i - N1;
            Wv16[k] = (_Float16)Wv[k];
        }
    }
}

// ---------------- Kernel 1: projections f,g,h — LDS-staged fp16 MFMA ----------------
// [R1/R5 measured-best 32-i version; ~12us]
__global__ __launch_bounds__(256) void proj_kernel(
    const float* __restrict__ x, const _Float16* __restrict__ Wc16,
    _Float16* __restrict__ Kf, _Float16* __restrict__ Qf,
    unsigned short* __restrict__ Vt)
{
    __shared__ float xsT[2][32][68];   // [buf][i][c] (68: 16B-aligned rows, pad)
    const int t    = threadIdx.x;
    const int w    = t >> 6;
    const int lane = t & 63;
    const int lh   = lane & 15;
    const int qd   = lane >> 4;
    const int b    = blockIdx.x >> 7;
    const int i0   = (blockIdx.x & 127) << 5;

    f32x4 acc[3][2];
    #pragma unroll
    for (int ot = 0; ot < 3; ot++)
        #pragma unroll
        for (int it = 0; it < 2; it++) { acc[ot][it][0]=0.f; acc[ot][it][1]=0.f; acc[ot][it][2]=0.f; acc[ot][it][3]=0.f; }

    const int ti8 = t & 7;           // i-group of 4
    const int tc2 = t >> 3;          // c-row 0..31
    const float* xbase = x + (size_t)b*CC*NN + i0 + ti8*4;
    const _Float16* wbase = Wc16 + (size_t)(w*48 + lh)*512 + qd*8;

    float4 st0, st1;
    half8  wcur[2][3], wnxt[2][3];

#define LOADX(ck) do {                                                        \
    st0 = *(const float4*)(xbase + (size_t)((ck)*64 + tc2)*NN);               \
    st1 = *(const float4*)(xbase + (size_t)((ck)*64 + 32 + tc2)*NN);          \
} while (0)
#define STOREX(p_) do {                                                       \
    xsT[p_][ti8*4+0][tc2]    = st0.x; xsT[p_][ti8*4+1][tc2]    = st0.y;       \
    xsT[p_][ti8*4+2][tc2]    = st0.z; xsT[p_][ti8*4+3][tc2]    = st0.w;       \
    xsT[p_][ti8*4+0][32+tc2] = st1.x; xsT[p_][ti8*4+1][32+tc2] = st1.y;       \
    xsT[p_][ti8*4+2][32+tc2] = st1.z; xsT[p_][ti8*4+3][32+tc2] = st1.w;       \
} while (0)
#define LOADW(ck, WD) do {                                                    \
    _Pragma("unroll")                                                         \
    for (int ks_ = 0; ks_ < 2; ks_++)                                         \
        _Pragma("unroll")                                                     \
        for (int ot_ = 0; ot_ < 3; ot_++)                                     \
            WD[ks_][ot_] = *(const half8*)(wbase + (size_t)(ot_*16)*512 + (ck)*64 + ks_*32); \
} while (0)

    LOADX(0); STOREX(0);
    LOADW(0, wcur);
    __syncthreads();

    #pragma unroll
    for (int ck = 0; ck < 8; ck++) {
        const int p = ck & 1;
        if (ck < 7) { LOADX(ck + 1); LOADW(ck + 1, wnxt); }

        #pragma unroll
        for (int ks = 0; ks < 2; ks++) {
            half8 xf[2];
            #pragma unroll
            for (int it = 0; it < 2; it++) {
                const float* xr = &xsT[p][it*16 + lh][ks*32 + qd*8];
                f32x4 xa = *(const f32x4*)xr;
                f32x4 xb = *(const f32x4*)(xr + 4);
                union { fp16x2 h2[4]; half8 h8; } u;
                u.h2[0] = __builtin_amdgcn_cvt_pkrtz(xa[0], xa[1]);
                u.h2[1] = __builtin_amdgcn_cvt_pkrtz(xa[2], xa[3]);
                u.h2[2] = __builtin_amdgcn_cvt_pkrtz(xb[0], xb[1]);
                u.h2[3] = __builtin_amdgcn_cvt_pkrtz(xb[2], xb[3]);
                xf[it] = u.h8;
            }
            #pragma unroll
            for (int ot = 0; ot < 3; ot++)
                #pragma unroll
                for (int it = 0; it < 2; it++)
                    acc[ot][it] = __builtin_amdgcn_mfma_f32_16x16x32_f16(wcur[ks][ot], xf[it], acc[ot][it], 0, 0, 0);
        }

        if (ck < 7) {
            STOREX(p ^ 1);
            #pragma unroll
            for (int ks_ = 0; ks_ < 2; ks_++)
                #pragma unroll
                for (int ot_ = 0; ot_ < 3; ot_++)
                    wcur[ks_][ot_] = wnxt[ks_][ot_];
        }
        __syncthreads();
    }
#undef LOADX
#undef STOREX
#undef LOADW

    #pragma unroll
    for (int ot = 0; ot < 3; ot++) {
        int g16 = w*3 + ot;          // 0..11
        int m   = g16 >> 2;
        int obase = (g16 & 3)*16 + qd*4;
        #pragma unroll
        for (int it = 0; it < 2; it++) {
            int ig = i0 + it*16 + lh;
            #pragma unroll
            for (int r = 0; r < 4; r++) {
                float v = acc[ot][it][r];
                int ol = obase + r;
                if (m == 0)       Kf[((size_t)b*NN + ig)*64 + ol] = (_Float16)v;
                else if (m == 1)  Qf[((size_t)b*NN + ig)*64 + ol] = (_Float16)v;
                else              Vt[((size_t)b*64 + ol)*NN + ig] = f2bf(v);
            }
        }
    }
}

// ---------------- Kernel 2: split-K flash attention — direct-L2 + explicit pipeline ----
// R10 showed direct-L2 traffic is right (FETCH 8.7MB, L2 reuse works) but per-tile
// load->MFMA dependency exposed full L2 latency (MfmaUtil 8%, VALU 22%). Fix:
// explicit register double-buffer for K (named kA/kB, manually unrolled x2 per
// rule #20 — no runtime-indexed buffers), so next-tile K loads issue a full tile
// (~600cy) ahead; V loads issue at tile top and are consumed after QK+softmax
// (~400cy cover). No LDS, no barriers, independent waves.
template<int SPLITS>
__global__ __launch_bounds__(256, 3) void attn_kernel(
    const _Float16* __restrict__ Kf, const _Float16* __restrict__ Qf,
    const unsigned short* __restrict__ Vt,
    _Float16* __restrict__ Po16, float* __restrict__ Pl)
{
    static_assert(NN % SPLITS == 0, "split");
    constexpr int KS = NN / SPLITS;   // keys per split
    constexpr int NT = KS / 32;       // 32-key MFMA tiles
    static_assert(NT % 2 == 0, "manual 2x unroll");

    const int t    = threadIdx.x;
    const int wv   = t >> 6;
    const int lane = t & 63;
    const int il   = lane & 31;
    const int h    = lane >> 5;

    // bijective XCD swizzle: blocks sharing (b,s) (same K/V) land on one XCD
    const int p  = blockIdx.x;
    const int v  = (p & 7) * (SPLITS * 16) + (p >> 3);
    const int jt = v & 31;
    const int bs = v >> 5;
    const int b  = bs / SPLITS;
    const int s  = bs % SPLITS;
    const int j0w  = jt*128 + wv*32;
    const int koff = s * KS;

    // Q fragments (B-operand), hoisted
    half8 qfr[4];
    {
        const _Float16* qp = Qf + ((size_t)b*NN + j0w + il)*64 + h*8;
        #pragma unroll
        for (int sl = 0; sl < 4; sl++) qfr[sl] = *(const half8*)(qp + sl*16);
    }

    f32x16 o_acc[2];
    #pragma unroll
    for (int dt = 0; dt < 2; dt++)
        #pragma unroll
        for (int r = 0; r < 16; r++) o_acc[dt][r] = 0.f;
    float l4[4] = {0.f, 0.f, 0.f, 0.f};

    const _Float16*       Kb  = Kf + ((size_t)b*NN + koff + il)*64 + h*8;
    const unsigned short* Vb0 = Vt + ((size_t)(b*64      + il))*NN + koff + h*8;
    const unsigned short* Vb1 = Vt + ((size_t)(b*64 + 32 + il))*NN + koff + h*8;

#define LOADK(KD, nt_) do {                                                   \
    const _Float16* kp_ = Kb + (size_t)((nt_)*32)*64;                         \
    KD[0] = *(const half8*)(kp_);                                             \
    KD[1] = *(const half8*)(kp_ + 16);                                        \
    KD[2] = *(const half8*)(kp_ + 32);                                        \
    KD[3] = *(const half8*)(kp_ + 48);                                        \
} while (0)

// Tile body using K buffer KC; prefetches tile (nt_+1) into KN when pf_.
#define TILE(KC, KN, nt_, pf_) do {                                           \
    const int ib_ = (nt_)*32;                                                 \
    short8 v00 = *(const short8*)(Vb0 + ib_);                                 \
    short8 v01 = *(const short8*)(Vb1 + ib_);                                 \
    short8 v10 = *(const short8*)(Vb0 + ib_ + 16);                            \
    short8 v11 = *(const short8*)(Vb1 + ib_ + 16);                            \
    if (pf_) LOADK(KN, (nt_) + 1);                                            \
    f32x16 sc;                                                                \
    _Pragma("unroll")                                                         \
    for (int r = 0; r < 16; r++) sc[r] = 0.f;                                 \
    sc = __builtin_amdgcn_mfma_f32_32x32x16_f16(KC[0], qfr[0], sc, 0, 0, 0);  \
    sc = __builtin_amdgcn_mfma_f32_32x32x16_f16(KC[1], qfr[1], sc, 0, 0, 0);  \
    sc = __builtin_amdgcn_mfma_f32_32x32x16_f16(KC[2], qfr[2], sc, 0, 0, 0);  \
    sc = __builtin_amdgcn_mfma_f32_32x32x16_f16(KC[3], qfr[3], sc, 0, 0, 0);  \
    _Pragma("unroll")                                                         \
    for (int r = 0; r < 16; r++) sc[r] = exp2f(sc[r]);                        \
    _Pragma("unroll")                                                         \
    for (int r = 0; r < 16; r++) l4[r & 3] += sc[r];                          \
    unsigned wA[8];                                                           \
    _Pragma("unroll")                                                         \
    for (int k = 0; k < 8; k++)                                               \
        asm("v_cvt_pk_bf16_f32 %0, %1, %2" : "=v"(wA[k]) : "v"(sc[2*k]), "v"(sc[2*k+1])); \
    asm("v_permlane32_swap_b32 %0, %1" : "+v"(wA[0]), "+v"(wA[2]));           \
    asm("v_permlane32_swap_b32 %0, %1" : "+v"(wA[1]), "+v"(wA[3]));           \
    asm("v_permlane32_swap_b32 %0, %1" : "+v"(wA[4]), "+v"(wA[6]));           \
    asm("v_permlane32_swap_b32 %0, %1" : "+v"(wA[5]), "+v"(wA[7]));           \
    union { unsigned u[4]; short8 s8; } pa0_, pa1_;                           \
    pa0_.u[0]=wA[0]; pa0_.u[1]=wA[1]; pa0_.u[2]=wA[2]; pa0_.u[3]=wA[3];       \
    pa1_.u[0]=wA[4]; pa1_.u[1]=wA[5]; pa1_.u[2]=wA[6]; pa1_.u[3]=wA[7];       \
    o_acc[0] = __builtin_amdgcn_mfma_f32_32x32x16_bf16(pa0_.s8, v00, o_acc[0], 0, 0, 0); \
    o_acc[1] = __builtin_amdgcn_mfma_f32_32x32x16_bf16(pa0_.s8, v01, o_acc[1], 0, 0, 0); \
    o_acc[0] = __builtin_amdgcn_mfma_f32_32x32x16_bf16(pa1_.s8, v10, o_acc[0], 0, 0, 0); \
    o_acc[1] = __builtin_amdgcn_mfma_f32_32x32x16_bf16(pa1_.s8, v11, o_acc[1], 0, 0, 0); \
} while (0)

    half8 kA[4], kB[4];
    LOADK(kA, 0);

    #pragma unroll 1
    for (int nt = 0; nt < NT; nt += 2) {
        TILE(kA, kB, nt, 1);                       // uses kA, prefetch nt+1 -> kB
        TILE(kB, kA, nt + 1, (nt + 2 < NT));       // uses kB, prefetch nt+2 -> kA
    }
#undef TILE
#undef LOADK

    // ---- epilogue: combine halves, normalize per-split, store ----
    float l_acc  = (l4[0] + l4[1]) + (l4[2] + l4[3]);
    float l_full = l_acc + __shfl_xor(l_acc, 32);
    float inv = 1.0f / l_full;

    const size_t pbase = (size_t)(s*4 + b)*NN + j0w;
    #pragma unroll
    for (int r = 0; r < 16; r++) {
        const int jr = (r & 3) + 8*(r >> 2) + 4*h;
        const float invr = __shfl(inv, jr);
        #pragma unroll
        for (int dt = 0; dt < 2; dt++)
            Po16[(pbase + jr)*64 + dt*32 + il] = (_Float16)(o_acc[dt][r] * invr);
    }
    if (h == 0) Pl[pbase + il] = l_full;
}

// ---------------- Kernel 3: fused combine + output projection + residual ----------------
// [R7 deduped/grid-1024 version; measured R9: ~25us warm, 56% BW]
template<int SPLITS>
__global__ __launch_bounds__(256) void outproj_kernel(
    const _Float16* __restrict__ Po16, const float* __restrict__ Pl,
    const _Float16* __restrict__ Wv16,
    const float* __restrict__ x, const float* __restrict__ gamma,
    float* __restrict__ out1, float* __restrict__ out2)
{
    __shared__ __align__(16) _Float16 sbM[16][72];  // merged sa^T [j][d], pad 72
    __shared__ float Osh[4][16][20];                // per-wave C-tile transpose
    const int t    = threadIdx.x;
    const int w    = t >> 6;
    const int lane = t & 63;
    const int lh   = lane & 15;
    const int qd   = lane >> 4;
    const int b    = blockIdx.x >> 8;
    const int j0   = (blockIdx.x & 255) << 4;
    const float g  = gamma[0];

    // ---- Phase 1: deduped split-K merge (threads 0..127; j = t&15, d8 = t>>4) ----
    if (t < 128) {
        const int jj = t & 15, d8 = t >> 4;
        float os[8];
        #pragma unroll
        for (int k = 0; k < 8; k++) os[k] = 0.f;
        float lsum = 0.f;
        #pragma unroll
        for (int s = 0; s < SPLITS; s++) {
            const size_t base = (size_t)(s*4 + b)*NN + j0 + jj;
            half8 vv = *(const half8*)(Po16 + base*64 + d8*8);
            float l  = Pl[base];
            #pragma unroll
            for (int k = 0; k < 8; k++) os[k] = fmaf(l, (float)vv[k], os[k]);
            lsum += l;
        }
        const float inv = 1.0f / lsum;
        union { fp16x2 h2[4]; half8 h8; } u;
        #pragma unroll
        for (int k = 0; k < 4; k++)
            u.h2[k] = __builtin_amdgcn_cvt_pkrtz(os[2*k]*inv, os[2*k+1]*inv);
        *(half8*)&sbM[jj][d8*8] = u.h8;
    }
    __syncthreads();

    const half8 sb0 = *(const half8*)&sbM[lh][qd*8];
    const half8 sb1 = *(const half8*)&sbM[lh][32 + qd*8];

    const int o_loc = lane >> 2;           // 0..15
    const int j4    = (lane & 3) * 4;      // 0,4,8,12

    #pragma unroll 2
    for (int ot8 = 0; ot8 < 8; ot8++) {
        const int ot = w*8 + ot8;

        // x residual load first: HBM latency hides under MFMA + transpose
        const size_t idx = ((size_t)b*CC + ot*16 + o_loc)*NN + j0 + j4;
        const f32x4 xv = *(const f32x4*)(x + idx);

        const size_t wbase = (size_t)(ot*16 + lh)*64 + qd*8;
        half8 a0 = *(const half8*)(Wv16 + wbase);
        half8 a1 = *(const half8*)(Wv16 + wbase + 32);

        f32x4 acc;
        acc[0]=0.f; acc[1]=0.f; acc[2]=0.f; acc[3]=0.f;
        acc = __builtin_amdgcn_mfma_f32_16x16x32_f16(a0, sb0, acc, 0, 0, 0);
        acc = __builtin_amdgcn_mfma_f32_16x16x32_f16(a1, sb1, acc, 0, 0, 0);

        #pragma unroll
        for (int r = 0; r < 4; r++)
            Osh[w][qd*4 + r][lh] = acc[r];
        asm volatile("s_waitcnt lgkmcnt(0)" ::: "memory");

        f32x4 vv = *(const f32x4*)&Osh[w][o_loc][j4];
        *(f32x4*)(out2 + idx) = vv;
        f32x4 r1;
        r1[0] = fmaf(g, vv[0], xv[0]); r1[1] = fmaf(g, vv[1], xv[1]);
        r1[2] = fmaf(g, vv[2], xv[2]); r1[3] = fmaf(g, vv[3], xv[3]);
        *(f32x4*)(out1 + idx) = r1;
        asm volatile("s_waitcnt lgkmcnt(0)" ::: "memory");  // WAR guard before next Osh write
    }
}

extern "C" void kernel_launch(void* const* d_in, const int* in_sizes, int n_in,
                              void* d_out, int out_size, void* d_ws, size_t ws_size,
                              hipStream_t stream) {
    const float* x     = (const float*)d_in[0];
    const float* Wf    = (const float*)d_in[1];
    const float* Wg    = (const float*)d_in[2];
    const float* Wh    = (const float*)d_in[3];
    const float* Wv    = (const float*)d_in[4];
    const float* gamma = (const float*)d_in[5];

    float* out1 = (float*)d_out;
    float* out2 = out1 + (size_t)BB*CC*NN;

    const size_t BND = (size_t)BB*NN*64;   // 1M elements
    const size_t need8 = BND*2*3 + BND*2*8 + (size_t)8*BB*NN*4
                       + (size_t)192*512*2 + (size_t)512*64*2;
    const int SPL = (ws_size >= need8) ? 8 : 4;

    char* wp = (char*)d_ws;
    _Float16*       Kf   = (_Float16*)wp;        wp += BND*2;            // 2 MB
    _Float16*       Qf   = (_Float16*)wp;        wp += BND*2;            // 2 MB
    unsigned short* Vt   = (unsigned short*)wp;  wp += BND*2;            // 2 MB
    _Float16*       Po16 = (_Float16*)wp;        wp += BND*2*SPL;        // 8/16 MB
    float*          Pl   = (float*)wp;           wp += (size_t)SPL*BB*NN*4;
    _Float16*       Wc16 = (_Float16*)wp;        wp += (size_t)192*512*2;
    _Float16*       Wv16 = (_Float16*)wp;

    prep_kernel<<<dim3(64), dim3(256), 0, stream>>>(Wf, Wg, Wh, Wv, Wc16, Wv16);
    proj_kernel<<<dim3(BB*128), dim3(256), 0, stream>>>(x, Wc16, Kf, Qf, Vt);
    if (SPL == 8) {
        attn_kernel<8><<<dim3(128*8), dim3(256), 0, stream>>>(Kf, Qf, Vt, Po16, Pl);
        outproj_kernel<8><<<dim3(BB*256), dim3(256), 0, stream>>>(Po16, Pl, Wv16, x, gamma, out1, out2);
    } else {
        attn_kernel<4><<<dim3(128*4), dim3(256), 0, stream>>>(Kf, Qf, Vt, Po16, Pl);
        outproj_kernel<4><<<dim3(BB*256), dim3(256), 0, stream>>>(Po16, Pl, Wv16, x, gamma, out1, out2);
    }
}

// Round 12
// 163.315 us; speedup vs baseline: 1.5949x; 1.2154x over previous
//
#include <hip/hip_runtime.h>
#include <cstddef>

#define BB 4
#define CC 512
#define NN 4096

using half8  = __attribute__((ext_vector_type(8))) _Float16;
using fp16x2 = __attribute__((ext_vector_type(2))) __fp16;
using short8 = __attribute__((ext_vector_type(8))) short;
using us8    = __attribute__((ext_vector_type(8))) unsigned short;
using f32x4  = __attribute__((ext_vector_type(4))) float;
using f32x16 = __attribute__((ext_vector_type(16))) float;

__device__ __forceinline__ unsigned short f2bf(float x) {
    unsigned int u = __float_as_uint(x);
    u += 0x7fffu + ((u >> 16) & 1u);
    return (unsigned short)(u >> 16);
}

// ---------------- Kernel 0: weight conversion to fp16 ----------------
__global__ __launch_bounds__(256) void prep_kernel(
    const float* __restrict__ Wf, const float* __restrict__ Wg,
    const float* __restrict__ Wh, const float* __restrict__ Wv,
    _Float16* __restrict__ Wc16, _Float16* __restrict__ Wv16)
{
    int idx = blockIdx.x * 256 + threadIdx.x;
    int stride = gridDim.x * 256;
    const int N1 = 192 * 512, N2 = 512 * 64;
    for (int i = idx; i < N1 + N2; i += stride) {
        if (i < N1) {
            int row = i >> 9, c = i & 511;
            const float* src = (row < 64) ? Wf : ((row < 128) ? Wg : Wh);
            float sc = (row >= 64 && row < 128) ? 1.4426950408889634f : 1.0f;
            Wc16[i] = (_Float16)(sc * src[(row & 63) * 512 + c]);
        } else {
            int k = i - N1;
            Wv16[k] = (_Float16)Wv[k];
        }
    }
}

// ---------------- Kernel 1: projections f,g,h — LDS-staged fp16 MFMA ----------------
// [R1/R5 measured-best 32-i version; ~12us]
__global__ __launch_bounds__(256) void proj_kernel(
    const float* __restrict__ x, const _Float16* __restrict__ Wc16,
    _Float16* __restrict__ Kf, _Float16* __restrict__ Qf,
    unsigned short* __restrict__ Vt)
{
    __shared__ float xsT[2][32][68];   // [buf][i][c] (68: 16B-aligned rows, pad)
    const int t    = threadIdx.x;
    const int w    = t >> 6;
    const int lane = t & 63;
    const int lh   = lane & 15;
    const int qd   = lane >> 4;
    const int b    = blockIdx.x >> 7;
    const int i0   = (blockIdx.x & 127) << 5;

    f32x4 acc[3][2];
    #pragma unroll
    for (int ot = 0; ot < 3; ot++)
        #pragma unroll
        for (int it = 0; it < 2; it++) { acc[ot][it][0]=0.f; acc[ot][it][1]=0.f; acc[ot][it][2]=0.f; acc[ot][it][3]=0.f; }

    const int ti8 = t & 7;           // i-group of 4
    const int tc2 = t >> 3;          // c-row 0..31
    const float* xbase = x + (size_t)b*CC*NN + i0 + ti8*4;
    const _Float16* wbase = Wc16 + (size_t)(w*48 + lh)*512 + qd*8;

    float4 st0, st1;
    half8  wcur[2][3], wnxt[2][3];

#define LOADX(ck) do {                                                        \
    st0 = *(const float4*)(xbase + (size_t)((ck)*64 + tc2)*NN);               \
    st1 = *(const float4*)(xbase + (size_t)((ck)*64 + 32 + tc2)*NN);          \
} while (0)
#define STOREX(p_) do {                                                       \
    xsT[p_][ti8*4+0][tc2]    = st0.x; xsT[p_][ti8*4+1][tc2]    = st0.y;       \
    xsT[p_][ti8*4+2][tc2]    = st0.z; xsT[p_][ti8*4+3][tc2]    = st0.w;       \
    xsT[p_][ti8*4+0][32+tc2] = st1.x; xsT[p_][ti8*4+1][32+tc2] = st1.y;       \
    xsT[p_][ti8*4+2][32+tc2] = st1.z; xsT[p_][ti8*4+3][32+tc2] = st1.w;       \
} while (0)
#define LOADW(ck, WD) do {                                                    \
    _Pragma("unroll")                                                         \
    for (int ks_ = 0; ks_ < 2; ks_++)                                         \
        _Pragma("unroll")                                                     \
        for (int ot_ = 0; ot_ < 3; ot_++)                                     \
            WD[ks_][ot_] = *(const half8*)(wbase + (size_t)(ot_*16)*512 + (ck)*64 + ks_*32); \
} while (0)

    LOADX(0); STOREX(0);
    LOADW(0, wcur);
    __syncthreads();

    #pragma unroll
    for (int ck = 0; ck < 8; ck++) {
        const int p = ck & 1;
        if (ck < 7) { LOADX(ck + 1); LOADW(ck + 1, wnxt); }

        #pragma unroll
        for (int ks = 0; ks < 2; ks++) {
            half8 xf[2];
            #pragma unroll
            for (int it = 0; it < 2; it++) {
                const float* xr = &xsT[p][it*16 + lh][ks*32 + qd*8];
                f32x4 xa = *(const f32x4*)xr;
                f32x4 xb = *(const f32x4*)(xr + 4);
                union { fp16x2 h2[4]; half8 h8; } u;
                u.h2[0] = __builtin_amdgcn_cvt_pkrtz(xa[0], xa[1]);
                u.h2[1] = __builtin_amdgcn_cvt_pkrtz(xa[2], xa[3]);
                u.h2[2] = __builtin_amdgcn_cvt_pkrtz(xb[0], xb[1]);
                u.h2[3] = __builtin_amdgcn_cvt_pkrtz(xb[2], xb[3]);
                xf[it] = u.h8;
            }
            #pragma unroll
            for (int ot = 0; ot < 3; ot++)
                #pragma unroll
                for (int it = 0; it < 2; it++)
                    acc[ot][it] = __builtin_amdgcn_mfma_f32_16x16x32_f16(wcur[ks][ot], xf[it], acc[ot][it], 0, 0, 0);
        }

        if (ck < 7) {
            STOREX(p ^ 1);
            #pragma unroll
            for (int ks_ = 0; ks_ < 2; ks_++)
                #pragma unroll
                for (int ot_ = 0; ot_ < 3; ot_++)
                    wcur[ks_][ot_] = wnxt[ks_][ot_];
        }
        __syncthreads();
    }
#undef LOADX
#undef STOREX
#undef LOADW

    #pragma unroll
    for (int ot = 0; ot < 3; ot++) {
        int g16 = w*3 + ot;          // 0..11
        int m   = g16 >> 2;
        int obase = (g16 & 3)*16 + qd*4;
        #pragma unroll
        for (int it = 0; it < 2; it++) {
            int ig = i0 + it*16 + lh;
            #pragma unroll
            for (int r = 0; r < 4; r++) {
                float v = acc[ot][it][r];
                int ol = obase + r;
                if (m == 0)       Kf[((size_t)b*NN + ig)*64 + ol] = (_Float16)v;
                else if (m == 1)  Qf[((size_t)b*NN + ig)*64 + ol] = (_Float16)v;
                else              Vt[((size_t)b*64 + ol)*NN + ig] = f2bf(v);
            }
        }
    }
}

// ---------------- Kernel 2: split-K flash attention, 32x32 swapped-QK^T ----------------
// [EXACT R1 measured-best version — LDS-staged via global_load_lds (coalesced 1KB
//  per inst), double-buffered, one __syncthreads cadence per chunk. R10/R11's
//  direct-from-L2 variants regressed 2-2.5x: per-lane fragment loads touch 32
//  distinct cache lines per instruction (4x transaction amplification) and the
//  TA pipe serializes. Staging exists to coalesce; keep it. ~33us, ~60% VALU-bound.]
template<int SPLITS>
__global__ __launch_bounds__(256, 3) void attn_kernel(
    const _Float16* __restrict__ Kf, const _Float16* __restrict__ Qf,
    const unsigned short* __restrict__ Vt,
    _Float16* __restrict__ Po16, float* __restrict__ Pl)
{
    static_assert(NN % SPLITS == 0, "split");
    constexpr int KS  = NN / SPLITS;   // keys per split
    constexpr int NCH = KS / 64;       // 64-key chunks

    __shared__ __align__(16) unsigned short Kb2[2][64*64];  // [i][c] swizzled 16B blocks
    __shared__ __align__(16) unsigned short Vb2[2][64*64];  // [d][i] swizzled 16B blocks

    const int t    = threadIdx.x;
    const int wv   = t >> 6;
    const int lane = t & 63;
    const int il   = lane & 31;
    const int h    = lane >> 5;

    // bijective XCD swizzle: blocks sharing (b,s) (same K/V) land on one XCD
    const int p  = blockIdx.x;
    const int v  = (p & 7) * (SPLITS * 16) + (p >> 3);
    const int jt = v & 31;
    const int bs = v >> 5;
    const int b  = bs / SPLITS;
    const int s  = bs % SPLITS;
    const int j0w  = jt*128 + wv*32;
    const int koff = s * KS;

    // Q fragments (B-operand), hoisted: lane supplies Q[c = sl*16 + h*8 + e][j = j0w + il]
    half8 qfr[4];
    {
        const _Float16* qp = Qf + ((size_t)b*NN + j0w + il)*64 + h*8;
        #pragma unroll
        for (int sl = 0; sl < 4; sl++) qfr[sl] = *(const half8*)(qp + sl*16);
    }

    f32x16 o_acc[2];
    #pragma unroll
    for (int dt = 0; dt < 2; dt++)
        #pragma unroll
        for (int r = 0; r < 16; r++) o_acc[dt][r] = 0.f;
    float l4[4] = {0.f, 0.f, 0.f, 0.f};

    // Staging bases. Two 16B slots per thread per buffer (K and V each):
    // linear LDS dest (wave-uniform base + lane*16), inverse-swizzled global SOURCE
    // (involution: slot c8 holds col block c8^(row&7)).
    const int slot0 = t, slot1 = 256 + t;
    const int ik0 = slot0 >> 3, sw0 = ((slot0 & 7) ^ (ik0 & 7)) << 3;
    const int ik1 = slot1 >> 3, sw1 = ((slot1 & 7) ^ (ik1 & 7)) << 3;
    const _Float16*       gk0 = Kf + ((size_t)b*NN + koff + ik0)*64 + sw0;
    const _Float16*       gk1 = Kf + ((size_t)b*NN + koff + ik1)*64 + sw1;
    const unsigned short* gv0 = Vt + ((size_t)b*64 + ik0)*NN + koff + sw0;
    const unsigned short* gv1 = Vt + ((size_t)b*64 + ik1)*NN + koff + sw1;

#define STAGE(ck, pb) do {                                                          \
    const size_t o64_ = (size_t)(ck)*64;                                            \
    __builtin_amdgcn_global_load_lds(                                               \
        (const __attribute__((address_space(1))) void*)(gk0 + o64_*64),             \
        (__attribute__((address_space(3))) void*)&Kb2[pb][(wv*64)*8], 16, 0, 0);    \
    __builtin_amdgcn_global_load_lds(                                               \
        (const __attribute__((address_space(1))) void*)(gk1 + o64_*64),             \
        (__attribute__((address_space(3))) void*)&Kb2[pb][(256 + wv*64)*8], 16, 0, 0); \
    __builtin_amdgcn_global_load_lds(                                               \
        (const __attribute__((address_space(1))) void*)(gv0 + o64_),                \
        (__attribute__((address_space(3))) void*)&Vb2[pb][(wv*64)*8], 16, 0, 0);    \
    __builtin_amdgcn_global_load_lds(                                               \
        (const __attribute__((address_space(1))) void*)(gv1 + o64_),                \
        (__attribute__((address_space(3))) void*)&Vb2[pb][(256 + wv*64)*8], 16, 0, 0); \
    } while (0)

    STAGE(0, 0);
    __syncthreads();

    for (int ck = 0; ck < NCH; ck++) {
        const int cb = ck & 1;
        if (ck + 1 < NCH) STAGE(ck + 1, cb ^ 1);

        const unsigned short* Kb = Kb2[cb];
        const unsigned short* Vb = Vb2[cb];

        #pragma unroll
        for (int isub = 0; isub < 2; isub++) {
            // ---- S^T tile: A = K[i][c] (i = isub*32 + il), B = Q[c][j] ----
            const int irow = isub*32 + il;
            const unsigned short* kr = Kb + irow*64;
            f32x16 sc;
            #pragma unroll
            for (int r = 0; r < 16; r++) sc[r] = 0.f;
            #pragma unroll
            for (int sl = 0; sl < 4; sl++) {
                half8 kf = *(const half8*)(kr + (((sl*2 + h) ^ (irow & 7)) << 3));
                sc = __builtin_amdgcn_mfma_f32_32x32x16_f16(kf, qfr[sl], sc, 0, 0, 0);
            }

            // ---- softmax numerator, lane-local (j = il); rows i = (r&3)+8*(r>>2)+4h ----
            float pq[16];
            #pragma unroll
            for (int r = 0; r < 16; r++) pq[r] = exp2f(sc[r]);
            #pragma unroll
            for (int r = 0; r < 16; r++) l4[r & 3] += pq[r];

            // ---- P -> bf16 A-fragments in-register (cvt_pk + permlane32_swap) ----
            unsigned wA[8];
            #pragma unroll
            for (int k = 0; k < 8; k++)
                asm("v_cvt_pk_bf16_f32 %0, %1, %2" : "=v"(wA[k]) : "v"(pq[2*k]), "v"(pq[2*k+1]));
            asm("v_permlane32_swap_b32 %0, %1" : "+v"(wA[0]), "+v"(wA[2]));
            asm("v_permlane32_swap_b32 %0, %1" : "+v"(wA[1]), "+v"(wA[3]));
            asm("v_permlane32_swap_b32 %0, %1" : "+v"(wA[4]), "+v"(wA[6]));
            asm("v_permlane32_swap_b32 %0, %1" : "+v"(wA[5]), "+v"(wA[7]));

            union { unsigned u[4]; short8 s8; } pa0, pa1;
            pa0.u[0]=wA[0]; pa0.u[1]=wA[1]; pa0.u[2]=wA[2]; pa0.u[3]=wA[3];
            pa1.u[0]=wA[4]; pa1.u[1]=wA[5]; pa1.u[2]=wA[6]; pa1.u[3]=wA[7];

            // ---- PV: A = P^T[j][i], B = V[i][d] ----
            #pragma unroll
            for (int isl = 0; isl < 2; isl++) {
                const short8 paf = isl ? pa1.s8 : pa0.s8;
                const int vc = isub*4 + isl*2 + h;
                #pragma unroll
                for (int dt = 0; dt < 2; dt++) {
                    const int drow = dt*32 + il;
                    short8 vf = *(const short8*)(Vb + drow*64 + ((vc ^ (drow & 7)) << 3));
                    o_acc[dt] = __builtin_amdgcn_mfma_f32_32x32x16_bf16(paf, vf, o_acc[dt], 0, 0, 0);
                }
            }
        }
        __syncthreads();   // drains staged loads (vmcnt) + orders buffer reuse
    }
#undef STAGE

    // ---- epilogue: combine halves, normalize per-split, store ----
    float l_acc  = (l4[0] + l4[1]) + (l4[2] + l4[3]);
    float l_full = l_acc + __shfl_xor(l_acc, 32);
    float inv = 1.0f / l_full;

    const size_t pbase = (size_t)(s*4 + b)*NN + j0w;
    #pragma unroll
    for (int r = 0; r < 16; r++) {
        const int jr = (r & 3) + 8*(r >> 2) + 4*h;
        const float invr = __shfl(inv, jr);
        #pragma unroll
        for (int dt = 0; dt < 2; dt++)
            Po16[(pbase + jr)*64 + dt*32 + il] = (_Float16)(o_acc[dt][r] * invr);
    }
    if (h == 0) Pl[pbase + il] = l_full;
}

// ---------------- Kernel 3: fused combine + output projection + residual ----------------
// [R7 deduped/grid-1024 version; measured R9: ~25us warm, 56% BW, ~70% of floor]
template<int SPLITS>
__global__ __launch_bounds__(256) void outproj_kernel(
    const _Float16* __restrict__ Po16, const float* __restrict__ Pl,
    const _Float16* __restrict__ Wv16,
    const float* __restrict__ x, const float* __restrict__ gamma,
    float* __restrict__ out1, float* __restrict__ out2)
{
    __shared__ __align__(16) _Float16 sbM[16][72];  // merged sa^T [j][d], pad 72
    __shared__ float Osh[4][16][20];                // per-wave C-tile transpose
    const int t    = threadIdx.x;
    const int w    = t >> 6;
    const int lane = t & 63;
    const int lh   = lane & 15;
    const int qd   = lane >> 4;
    const int b    = blockIdx.x >> 8;
    const int j0   = (blockIdx.x & 255) << 4;
    const float g  = gamma[0];

    // ---- Phase 1: deduped split-K merge (threads 0..127; j = t&15, d8 = t>>4) ----
    if (t < 128) {
        const int jj = t & 15, d8 = t >> 4;
        float os[8];
        #pragma unroll
        for (int k = 0; k < 8; k++) os[k] = 0.f;
        float lsum = 0.f;
        #pragma unroll
        for (int s = 0; s < SPLITS; s++) {
            const size_t base = (size_t)(s*4 + b)*NN + j0 + jj;
            half8 vv = *(const half8*)(Po16 + base*64 + d8*8);
            float l  = Pl[base];
            #pragma unroll
            for (int k = 0; k < 8; k++) os[k] = fmaf(l, (float)vv[k], os[k]);
            lsum += l;
        }
        const float inv = 1.0f / lsum;
        union { fp16x2 h2[4]; half8 h8; } u;
        #pragma unroll
        for (int k = 0; k < 4; k++)
            u.h2[k] = __builtin_amdgcn_cvt_pkrtz(os[2*k]*inv, os[2*k+1]*inv);
        *(half8*)&sbM[jj][d8*8] = u.h8;
    }
    __syncthreads();

    const half8 sb0 = *(const half8*)&sbM[lh][qd*8];
    const half8 sb1 = *(const half8*)&sbM[lh][32 + qd*8];

    const int o_loc = lane >> 2;           // 0..15
    const int j4    = (lane & 3) * 4;      // 0,4,8,12

    #pragma unroll 2
    for (int ot8 = 0; ot8 < 8; ot8++) {
        const int ot = w*8 + ot8;

        // x residual load first: HBM latency hides under MFMA + transpose
        const size_t idx = ((size_t)b*CC + ot*16 + o_loc)*NN + j0 + j4;
        const f32x4 xv = *(const f32x4*)(x + idx);

        const size_t wbase = (size_t)(ot*16 + lh)*64 + qd*8;
        half8 a0 = *(const half8*)(Wv16 + wbase);
        half8 a1 = *(const half8*)(Wv16 + wbase + 32);

        f32x4 acc;
        acc[0]=0.f; acc[1]=0.f; acc[2]=0.f; acc[3]=0.f;
        acc = __builtin_amdgcn_mfma_f32_16x16x32_f16(a0, sb0, acc, 0, 0, 0);
        acc = __builtin_amdgcn_mfma_f32_16x16x32_f16(a1, sb1, acc, 0, 0, 0);

        #pragma unroll
        for (int r = 0; r < 4; r++)
            Osh[w][qd*4 + r][lh] = acc[r];
        asm volatile("s_waitcnt lgkmcnt(0)" ::: "memory");

        f32x4 vv = *(const f32x4*)&Osh[w][o_loc][j4];
        *(f32x4*)(out2 + idx) = vv;
        f32x4 r1;
        r1[0] = fmaf(g, vv[0], xv[0]); r1[1] = fmaf(g, vv[1], xv[1]);
        r1[2] = fmaf(g, vv[2], xv[2]); r1[3] = fmaf(g, vv[3], xv[3]);
        *(f32x4*)(out1 + idx) = r1;
        asm volatile("s_waitcnt lgkmcnt(0)" ::: "memory");  // WAR guard before next Osh write
    }
}

extern "C" void kernel_launch(void* const* d_in, const int* in_sizes, int n_in,
                              void* d_out, int out_size, void* d_ws, size_t ws_size,
                              hipStream_t stream) {
    const float* x     = (const float*)d_in[0];
    const float* Wf    = (const float*)d_in[1];
    const float* Wg    = (const float*)d_in[2];
    const float* Wh    = (const float*)d_in[3];
    const float* Wv    = (const float*)d_in[4];
    const float* gamma = (const float*)d_in[5];

    float* out1 = (float*)d_out;
    float* out2 = out1 + (size_t)BB*CC*NN;

    const size_t BND = (size_t)BB*NN*64;   // 1M elements
    const size_t need8 = BND*2*3 + BND*2*8 + (size_t)8*BB*NN*4
                       + (size_t)192*512*2 + (size_t)512*64*2;
    const int SPL = (ws_size >= need8) ? 8 : 4;

    char* wp = (char*)d_ws;
    _Float16*       Kf   = (_Float16*)wp;        wp += BND*2;            // 2 MB
    _Float16*       Qf   = (_Float16*)wp;        wp += BND*2;            // 2 MB
    unsigned short* Vt   = (unsigned short*)wp;  wp += BND*2;            // 2 MB
    _Float16*       Po16 = (_Float16*)wp;        wp += BND*2*SPL;        // 8/16 MB
    float*          Pl   = (float*)wp;           wp += (size_t)SPL*BB*NN*4;
    _Float16*       Wc16 = (_Float16*)wp;        wp += (size_t)192*512*2;
    _Float16*       Wv16 = (_Float16*)wp;

    prep_kernel<<<dim3(64), dim3(256), 0, stream>>>(Wf, Wg, Wh, Wv, Wc16, Wv16);
    proj_kernel<<<dim3(BB*128), dim3(256), 0, stream>>>(x, Wc16, Kf, Qf, Vt);
    if (SPL == 8) {
        attn_kernel<8><<<dim3(128*8), dim3(256), 0, stream>>>(Kf, Qf, Vt, Po16, Pl);
        outproj_kernel<8><<<dim3(BB*256), dim3(256), 0, stream>>>(Po16, Pl, Wv16, x, gamma, out1, out2);
    } else {
        attn_kernel<4><<<dim3(128*4), dim3(256), 0, stream>>>(Kf, Qf, Vt, Po16, Pl);
        outproj_kernel<4><<<dim3(BB*256), dim3(256), 0, stream>>>(Po16, Pl, Wv16, x, gamma, out1, out2);
    }
}